// Round 9
// baseline (479.318 us; speedup 1.0000x reference)
//
#include <hip/hip_runtime.h>

typedef unsigned short ushortT;
typedef __attribute__((ext_vector_type(8))) short bf16x8;
typedef __attribute__((ext_vector_type(4))) float f32x4;

constexpr int Ec = 1024;   // embed
constexpr int Hc = 16;     // heads
constexpr int Dc = 64;     // head dim
constexpr int Bc = 4;      // batch
constexpr int Sc = 1024;   // seq
constexpr int XN = Bc * Sc * Ec;          // 4194304 (elements of one B,S,E tensor)
constexpr int LDW = 72;    // LDS row stride in bf16 (144B: 16B-aligned, good bank spread)

#define MFMA_BF16 __builtin_amdgcn_mfma_f32_16x16x32_bf16

__device__ __forceinline__ ushortT f2bf(float f) {
  union { float f; unsigned int u; } x{f};
  unsigned int r = x.u + 0x7fffu + ((x.u >> 16) & 1u);   // RNE
  return (ushortT)(r >> 16);
}

// ---------------------------------------------------------------------------
// K0: cast fp32 inputs/weights -> bf16 workspace copies.
// ---------------------------------------------------------------------------
struct US8 { ushortT u[8]; };

__global__ __launch_bounds__(256) void k_cast(
    const float* __restrict__ q, const float* __restrict__ k,
    const float* __restrict__ v, const float* __restrict__ wi,
    const float* __restrict__ wo,
    ushortT* __restrict__ oq, ushortT* __restrict__ ok,
    ushortT* __restrict__ ov, ushortT* __restrict__ owi,
    ushortT* __restrict__ owo)
{
  const int seg = blockIdx.y;
  const float* src; ushortT* dst; int n;
  if      (seg == 0) { src = q;  dst = oq;  n = XN; }
  else if (seg == 1) { src = k;  dst = ok;  n = XN; }
  else if (seg == 2) { src = v;  dst = ov;  n = XN; }
  else if (seg == 3) { src = wi; dst = owi; n = 3 * Ec * Ec; }
  else               { src = wo; dst = owo; n = Ec * Ec; }
  int base = (blockIdx.x * 256 + threadIdx.x) * 8;
  if (base >= n) return;
  float4 a = *reinterpret_cast<const float4*>(src + base);
  float4 b = *reinterpret_cast<const float4*>(src + base + 4);
  US8 o;
  o.u[0] = f2bf(a.x); o.u[1] = f2bf(a.y); o.u[2] = f2bf(a.z); o.u[3] = f2bf(a.w);
  o.u[4] = f2bf(b.x); o.u[5] = f2bf(b.y); o.u[6] = f2bf(b.z); o.u[7] = f2bf(b.w);
  *reinterpret_cast<US8*>(dst + base) = o;
}

// ---------------------------------------------------------------------------
// K1: QKV projection, bf16 MFMA. (unchanged)
// ---------------------------------------------------------------------------
__global__ __launch_bounds__(256) void k_qkv_mfma(
    const ushortT* __restrict__ xq, const ushortT* __restrict__ xk,
    const ushortT* __restrict__ xv, const ushortT* __restrict__ wi,
    const float* __restrict__ bias, ushortT* __restrict__ qkv)
{
  __shared__ __align__(16) ushortT As[128][LDW];
  __shared__ __align__(16) ushortT Bs[128][LDW];
  const int tid = threadIdx.x;
  const int lane = tid & 63, wid = tid >> 6;
  const int wm = wid >> 1, wn = wid & 1;
  const int li = lane & 15, gi = lane >> 4;
  const int m0 = blockIdx.x * 128, n0 = blockIdx.y * 128;
  const int third = n0 >> 10;
  const ushortT* x = (third == 0) ? xq : (third == 1) ? xk : xv;

  f32x4 acc[4][4] = {};

  for (int k0 = 0; k0 < 1024; k0 += 64) {
    __syncthreads();
#pragma unroll
    for (int i = 0; i < 4; ++i) {
      int c = tid + i * 256;                 // 0..1023
      int row = c >> 3, col = (c & 7) * 8;
      *reinterpret_cast<uint4*>(&As[row][col]) =
          *reinterpret_cast<const uint4*>(x + (size_t)(m0 + row) * 1024 + k0 + col);
      *reinterpret_cast<uint4*>(&Bs[row][col]) =
          *reinterpret_cast<const uint4*>(wi + (size_t)(n0 + row) * 1024 + k0 + col);
    }
    __syncthreads();
#pragma unroll
    for (int ks = 0; ks < 2; ++ks) {
      bf16x8 a[4], b[4];
#pragma unroll
      for (int t = 0; t < 4; ++t) {
        a[t] = *reinterpret_cast<const bf16x8*>(&As[wm * 64 + t * 16 + li][ks * 32 + gi * 8]);
        b[t] = *reinterpret_cast<const bf16x8*>(&Bs[wn * 64 + t * 16 + li][ks * 32 + gi * 8]);
      }
#pragma unroll
      for (int mi = 0; mi < 4; ++mi)
#pragma unroll
        for (int ni = 0; ni < 4; ++ni)
          acc[mi][ni] = MFMA_BF16(a[mi], b[ni], acc[mi][ni], 0, 0, 0);
    }
  }

  const float scale = (third == 0) ? 0.125f : 1.0f;
#pragma unroll
  for (int ni = 0; ni < 4; ++ni) {
    int n = n0 + wn * 64 + ni * 16 + li;
    float bv = bias[n];
    int h = (n >> 6) & 15, d = n & 63;
#pragma unroll
    for (int mi = 0; mi < 4; ++mi)
#pragma unroll
      for (int r = 0; r < 4; ++r) {
        int m = m0 + wm * 64 + mi * 16 + gi * 4 + r;
        int b_ = m >> 10, s = m & 1023;
        size_t o = ((((size_t)third * Bc + b_) * Hc + h) * Sc + s) * Dc + d;
        qkv[o] = f2bf((acc[mi][ni][r] + bv) * scale);
      }
  }
}

// ---------------------------------------------------------------------------
// K2: flash attention, bf16 MFMA. Writes ctx + fused offrow = m + ln l + ln 16.
// (unchanged)
// ---------------------------------------------------------------------------
__global__ __launch_bounds__(256) void k_flash_mfma(
    const ushortT* __restrict__ qkv, ushortT* __restrict__ ctx,
    float* __restrict__ offrow)
{
  __shared__ __align__(16) ushortT Qs[64][LDW];
  __shared__ __align__(16) ushortT Ks[64][LDW];
  __shared__ __align__(16) ushortT Vt[64][LDW];   // [d][k'] permuted
  __shared__ __align__(16) ushortT Ps[64][LDW];   // [q][k'] permuted
  const int tid = threadIdx.x;
  const int lane = tid & 63, w = tid >> 6;
  const int li = lane & 15, gi = lane >> 4;
  const int s0 = blockIdx.x * 64;
  const int bh = blockIdx.z * Hc + blockIdx.y;
  const ushortT* Q = qkv;
  const ushortT* K = qkv + (size_t)XN;
  const ushortT* V = qkv + (size_t)2 * XN;
  const size_t bhb = (size_t)bh * Sc * Dc;

#pragma unroll
  for (int i = 0; i < 2; ++i) {
    int c = tid + i * 256;
    int row = c >> 3, col = (c & 7) * 8;
    *reinterpret_cast<uint4*>(&Qs[row][col]) =
        *reinterpret_cast<const uint4*>(Q + bhb + (size_t)(s0 + row) * 64 + col);
  }

  f32x4 oa[4] = {};
  float m_r[4], l_r[4];
#pragma unroll
  for (int r = 0; r < 4; ++r) { m_r[r] = -1e30f; l_r[r] = 0.f; }

  // V staging map: pair id vp in [0,32), d-chunk vd0; pair rows (ka, ka+16)
  const int vp = tid & 31;
  const int vd0 = (tid >> 5) * 8;
  const int ka = (vp & 15) + (vp >> 4) * 32;
  const int kpb = 8 * (vp & 15) + 4 * (vp >> 4);  // byte offset of k'-pair in Vt row

  for (int kt = 0; kt < 16; ++kt) {
    const int k0 = kt * 64;
    uint4 kreg[2];
#pragma unroll
    for (int i = 0; i < 2; ++i) {
      int c = tid + i * 256;
      int row = c >> 3, col = (c & 7) * 8;
      kreg[i] = *reinterpret_cast<const uint4*>(K + bhb + (size_t)(k0 + row) * 64 + col);
    }
    uint4 va = *reinterpret_cast<const uint4*>(V + bhb + (size_t)(k0 + ka) * 64 + vd0);
    uint4 vb = *reinterpret_cast<const uint4*>(V + bhb + (size_t)(k0 + ka + 16) * 64 + vd0);
    __syncthreads();   // prior tile's LDS reads complete
#pragma unroll
    for (int i = 0; i < 2; ++i) {
      int c = tid + i * 256;
      int row = c >> 3, col = (c & 7) * 8;
      *reinterpret_cast<uint4*>(&Ks[row][col]) = kreg[i];
    }
    const ushortT* pa_ = reinterpret_cast<const ushortT*>(&va);
    const ushortT* pb_ = reinterpret_cast<const ushortT*>(&vb);
#pragma unroll
    for (int i = 0; i < 8; ++i) {
      unsigned int u = (unsigned int)pa_[i] | ((unsigned int)pb_[i] << 16);
      *reinterpret_cast<unsigned int*>(
          reinterpret_cast<char*>(&Vt[vd0 + i][0]) + kpb) = u;
    }
    __syncthreads();   // staged

    // QK^T
    f32x4 sc[4] = {};
#pragma unroll
    for (int ds = 0; ds < 2; ++ds) {
      bf16x8 aq = *reinterpret_cast<const bf16x8*>(&Qs[w * 16 + li][ds * 32 + gi * 8]);
#pragma unroll
      for (int nf = 0; nf < 4; ++nf) {
        bf16x8 bk = *reinterpret_cast<const bf16x8*>(&Ks[nf * 16 + li][ds * 32 + gi * 8]);
        sc[nf] = MFMA_BF16(aq, bk, sc[nf], 0, 0, 0);
      }
    }

    // online softmax (wave-local; rows r live in acc component r)
    float esc[4];
#pragma unroll
    for (int r = 0; r < 4; ++r) {
      float v = fmaxf(fmaxf(sc[0][r], sc[1][r]), fmaxf(sc[2][r], sc[3][r]));
      v = fmaxf(v, __shfl_xor(v, 1));
      v = fmaxf(v, __shfl_xor(v, 2));
      v = fmaxf(v, __shfl_xor(v, 4));
      v = fmaxf(v, __shfl_xor(v, 8));
      float mnew = fmaxf(m_r[r], v);
      esc[r] = __expf(m_r[r] - mnew);
      m_r[r] = mnew;
    }
    float p[4][4];
#pragma unroll
    for (int r = 0; r < 4; ++r) {
      float s = 0.f;
#pragma unroll
      for (int nf = 0; nf < 4; ++nf) { p[nf][r] = __expf(sc[nf][r] - m_r[r]); s += p[nf][r]; }
      s += __shfl_xor(s, 1); s += __shfl_xor(s, 2);
      s += __shfl_xor(s, 4); s += __shfl_xor(s, 8);
      l_r[r] = l_r[r] * esc[r] + s;
#pragma unroll
      for (int nf = 0; nf < 4; ++nf) oa[nf][r] *= esc[r];
    }
    // pack P (bf16) into Ps rows (wave-private): cols k' = 4*li + nf
#pragma unroll
    for (int r = 0; r < 4; ++r) {
      unsigned int u0 = (unsigned int)f2bf(p[0][r]) | ((unsigned int)f2bf(p[1][r]) << 16);
      unsigned int u1 = (unsigned int)f2bf(p[2][r]) | ((unsigned int)f2bf(p[3][r]) << 16);
      uint2 uu; uu.x = u0; uu.y = u1;
      *reinterpret_cast<uint2*>(
          reinterpret_cast<char*>(&Ps[w * 16 + gi * 4 + r][0]) + li * 8) = uu;
    }
    // PV (contraction over permuted k'; P and Vt use the same permutation)
#pragma unroll
    for (int ks = 0; ks < 2; ++ks) {
      bf16x8 pa = *reinterpret_cast<const bf16x8*>(&Ps[w * 16 + li][ks * 32 + gi * 8]);
#pragma unroll
      for (int nf = 0; nf < 4; ++nf) {
        bf16x8 vv = *reinterpret_cast<const bf16x8*>(&Vt[nf * 16 + li][ks * 32 + gi * 8]);
        oa[nf] = MFMA_BF16(pa, vv, oa[nf], 0, 0, 0);
      }
    }
  }

  float inv[4];
#pragma unroll
  for (int r = 0; r < 4; ++r) inv[r] = 1.0f / l_r[r];
#pragma unroll
  for (int nf = 0; nf < 4; ++nf)
#pragma unroll
    for (int r = 0; r < 4; ++r) {
      int q = s0 + w * 16 + gi * 4 + r;
      ctx[bhb + (size_t)q * 64 + nf * 16 + li] = f2bf(oa[nf][r] * inv[r]);
    }
  if (li == 0) {
#pragma unroll
    for (int r = 0; r < 4; ++r) {
      int q = s0 + w * 16 + gi * 4 + r;
      // fused softmax offset: exp(s - off) = exp(s - m) / (16 * l)
      offrow[(size_t)bh * Sc + q] = m_r[r] + __logf(l_r[r]) + 2.77258872f;
    }
  }
}

// ---------------------------------------------------------------------------
// K3: out projection, bf16 MFMA. (unchanged)
// ---------------------------------------------------------------------------
__global__ __launch_bounds__(256) void k_outproj_mfma(
    const ushortT* __restrict__ ctx, const ushortT* __restrict__ wo,
    const float* __restrict__ bias, float* __restrict__ out)
{
  __shared__ __align__(16) ushortT As[128][LDW];
  __shared__ __align__(16) ushortT Bs[128][LDW];
  const int tid = threadIdx.x;
  const int lane = tid & 63, wid = tid >> 6;
  const int wm = wid >> 1, wn = wid & 1;
  const int li = lane & 15, gi = lane >> 4;
  const int m0 = blockIdx.x * 128, n0 = blockIdx.y * 128;

  f32x4 acc[4][4] = {};

  for (int k0 = 0; k0 < 1024; k0 += 64) {
    const int h = k0 >> 6;          // BK==Dc: one head per K-step
    __syncthreads();
#pragma unroll
    for (int i = 0; i < 4; ++i) {
      int c = tid + i * 256;
      int row = c >> 3, col = (c & 7) * 8;    // col < 64 == within head
      int m = m0 + row;
      int b_ = m >> 10, s = m & 1023;
      *reinterpret_cast<uint4*>(&As[row][col]) =
          *reinterpret_cast<const uint4*>(
              ctx + (((size_t)b_ * Hc + h) * Sc + s) * Dc + col);
      *reinterpret_cast<uint4*>(&Bs[row][col]) =
          *reinterpret_cast<const uint4*>(wo + (size_t)(n0 + row) * 1024 + k0 + col);
    }
    __syncthreads();
#pragma unroll
    for (int ks = 0; ks < 2; ++ks) {
      bf16x8 a[4], b[4];
#pragma unroll
      for (int t = 0; t < 4; ++t) {
        a[t] = *reinterpret_cast<const bf16x8*>(&As[wm * 64 + t * 16 + li][ks * 32 + gi * 8]);
        b[t] = *reinterpret_cast<const bf16x8*>(&Bs[wn * 64 + t * 16 + li][ks * 32 + gi * 8]);
      }
#pragma unroll
      for (int mi = 0; mi < 4; ++mi)
#pragma unroll
        for (int ni = 0; ni < 4; ++ni)
          acc[mi][ni] = MFMA_BF16(a[mi], b[ni], acc[mi][ni], 0, 0, 0);
    }
  }

#pragma unroll
  for (int ni = 0; ni < 4; ++ni) {
    int n = n0 + wn * 64 + ni * 16 + li;
    float bv = bias[n];
#pragma unroll
    for (int mi = 0; mi < 4; ++mi)
#pragma unroll
      for (int r = 0; r < 4; ++r) {
        int m = m0 + wm * 64 + mi * 16 + gi * 4 + r;
        out[(size_t)m * 1024 + n] = acc[mi][ni][r] + bv;
      }
  }
}

// ---------------------------------------------------------------------------
// K4: head-averaged attention weights * gate, bf16 MFMA, NO LDS.
// Explicit 2-deep software pipeline: named A/B fragment sets; LOADH(h+1)
// issued in source order BEFORE COMPUTE(h) so ~10 dwordx4/head stay in
// flight across a full compute phase (prev round showed compiler alone
// keeps ~1 outstanding miss/wave -> 88us latency plateau).
// ---------------------------------------------------------------------------
__global__ __launch_bounds__(256, 4) void k_avggate_mfma(
    const ushortT* __restrict__ qkv, const float* __restrict__ offrow,
    const float* __restrict__ gate, float* __restrict__ out1)
{
  const int tid = threadIdx.x;
  const int lane = tid & 63, w = tid >> 6;
  const int li = lane & 15, gi = lane >> 4;
  const int c0 = blockIdx.x * 64;
  const int s0 = blockIdx.y * 64;
  const int b = blockIdx.z;
  constexpr size_t HS = (size_t)Sc * Dc;            // per-head elements
  const ushortT* Qb = qkv + (size_t)b * Hc * HS;
  const ushortT* Kb = qkv + (size_t)XN + (size_t)b * Hc * HS;

  const int qrow = s0 + w * 16 + li;                // A-frag row (per lane)
  const int qoff = s0 + w * 16 + gi * 4;            // C/D rows (per lane)
  const size_t qa = (size_t)qrow * 64 + gi * 8;     // + ds*32
  size_t ka[4];
#pragma unroll
  for (int nf = 0; nf < 4; ++nf)
    ka[nf] = (size_t)(c0 + nf * 16 + li) * 64 + gi * 8;
  const float* offb = offrow + (size_t)b * Hc * Sc + qoff;

  f32x4 avg[4] = {};
  bf16x8 aqA[2], bkA[2][4];
  bf16x8 aqB[2], bkB[2][4];

#define LOADH(hh, aq, bk)                                                     \
  do {                                                                        \
    const ushortT* Qh = Qb + (size_t)(hh) * HS;                               \
    const ushortT* Kh = Kb + (size_t)(hh) * HS;                               \
    aq[0] = *reinterpret_cast<const bf16x8*>(Qh + qa);                        \
    aq[1] = *reinterpret_cast<const bf16x8*>(Qh + qa + 32);                   \
    _Pragma("unroll")                                                         \
    for (int ds = 0; ds < 2; ++ds)                                            \
      _Pragma("unroll")                                                       \
      for (int nf = 0; nf < 4; ++nf)                                          \
        bk[ds][nf] = *reinterpret_cast<const bf16x8*>(Kh + ka[nf] + ds * 32); \
  } while (0)

#define COMPUTEH(hh, aq, bk)                                                  \
  do {                                                                        \
    float4 of = *reinterpret_cast<const float4*>(offb + (size_t)(hh) * Sc);   \
    float ofa[4] = {of.x, of.y, of.z, of.w};                                  \
    f32x4 sc[4] = {};                                                         \
    _Pragma("unroll")                                                         \
    for (int ds = 0; ds < 2; ++ds)                                            \
      _Pragma("unroll")                                                       \
      for (int nf = 0; nf < 4; ++nf)                                          \
        sc[nf] = MFMA_BF16(aq[ds], bk[ds][nf], sc[nf], 0, 0, 0);              \
    _Pragma("unroll")                                                         \
    for (int nf = 0; nf < 4; ++nf)                                            \
      _Pragma("unroll")                                                       \
      for (int r = 0; r < 4; ++r)                                             \
        avg[nf][r] += __expf(sc[nf][r] - ofa[r]);                             \
  } while (0)

  LOADH(0, aqA, bkA);
#pragma unroll
  for (int h = 0; h < Hc; h += 2) {
    LOADH(h + 1, aqB, bkB);        // prefetch next while computing A
    COMPUTEH(h, aqA, bkA);
    if (h + 2 < Hc) LOADH(h + 2, aqA, bkA);
    COMPUTEH(h + 1, aqB, bkB);
  }
#undef LOADH
#undef COMPUTEH

#pragma unroll
  for (int nf = 0; nf < 4; ++nf)
#pragma unroll
    for (int r = 0; r < 4; ++r) {
      int q = qoff + r;
      size_t o = ((size_t)b * Sc + q) * Sc + c0 + nf * 16 + li;
      out1[o] = avg[nf][r] * gate[o];
    }
}

// ---------------------------------------------------------------------------
// K5: in-place row renormalization: x / (sum(x) + 1e-12)
// ---------------------------------------------------------------------------
__global__ __launch_bounds__(256) void k_renorm(float* __restrict__ out1)
{
  __shared__ float wsum[4];
  const int tid = threadIdx.x;
  float* row = out1 + (size_t)blockIdx.x * Sc;
  float4 v = *reinterpret_cast<const float4*>(row + tid * 4);
  float s = v.x + v.y + v.z + v.w;
#pragma unroll
  for (int off = 1; off < 64; off <<= 1) s += __shfl_xor(s, off);
  if ((tid & 63) == 0) wsum[tid >> 6] = s;
  __syncthreads();
  float inv = 1.0f / (wsum[0] + wsum[1] + wsum[2] + wsum[3] + 1e-12f);
  v.x *= inv; v.y *= inv; v.z *= inv; v.w *= inv;
  *reinterpret_cast<float4*>(row + tid * 4) = v;
}

// ---------------------------------------------------------------------------
extern "C" void kernel_launch(void* const* d_in, const int* in_sizes, int n_in,
                              void* d_out, int out_size, void* d_ws, size_t ws_size,
                              hipStream_t stream) {
  const float* query = (const float*)d_in[0];
  const float* key   = (const float*)d_in[1];
  const float* value = (const float*)d_in[2];
  const float* gate  = (const float*)d_in[3];
  const float* w_in  = (const float*)d_in[4];
  const float* b_in  = (const float*)d_in[5];
  const float* w_out = (const float*)d_in[6];
  const float* b_out = (const float*)d_in[7];

  float* out0 = (float*)d_out;                       // attn_output (B,S,E)
  float* out1 = out0 + (size_t)Bc * Sc * Ec;         // gated (B,S,S)

  // bf16 workspace layout (ushort elements)
  ushortT* xq   = (ushortT*)d_ws;                    // 4M
  ushortT* xk   = xq + (size_t)XN;                   // 4M
  ushortT* xv   = xk + (size_t)XN;                   // 4M
  ushortT* wi   = xv + (size_t)XN;                   // 3M
  ushortT* wo   = wi + (size_t)3 * Ec * Ec;          // 1M
  ushortT* qkvb = wo + (size_t)Ec * Ec;              // 12M (3,B,H,S,D)
  ushortT* ctxb = xq;                                // alias: xq dead after k_qkv
  float* offrow = (float*)(qkvb + (size_t)3 * XN);   // 64K (m + ln l + ln 16)

  hipLaunchKernelGGL(k_cast, dim3(2048, 5), dim3(256), 0, stream,
                     query, key, value, w_in, w_out, xq, xk, xv, wi, wo);
  hipLaunchKernelGGL(k_qkv_mfma, dim3(32, 24), dim3(256), 0, stream,
                     xq, xk, xv, wi, b_in, qkvb);
  hipLaunchKernelGGL(k_flash_mfma, dim3(16, 16, 4), dim3(256), 0, stream,
                     qkvb, ctxb, offrow);
  hipLaunchKernelGGL(k_outproj_mfma, dim3(32, 8), dim3(256), 0, stream,
                     ctxb, wo, b_out, out0);
  hipLaunchKernelGGL(k_avggate_mfma, dim3(16, 16, 4), dim3(256), 0, stream,
                     qkvb, offrow, gate, out1);
  hipLaunchKernelGGL(k_renorm, dim3(Bc * Sc), dim3(256), 0, stream, out1);
}

// Round 10
// 390.704 us; speedup vs baseline: 1.2268x; 1.2268x over previous
//
#include <hip/hip_runtime.h>

typedef unsigned short ushortT;
typedef __attribute__((ext_vector_type(8))) short bf16x8;
typedef __attribute__((ext_vector_type(4))) float f32x4;

constexpr int Ec = 1024;   // embed
constexpr int Hc = 16;     // heads
constexpr int Dc = 64;     // head dim
constexpr int Bc = 4;      // batch
constexpr int Sc = 1024;   // seq
constexpr int XN = Bc * Sc * Ec;          // 4194304 (elements of one B,S,E tensor)
constexpr int LDW = 72;    // LDS row stride in bf16 (144B: 16B-aligned, good bank spread)

#define MFMA_BF16 __builtin_amdgcn_mfma_f32_16x16x32_bf16

__device__ __forceinline__ ushortT f2bf(float f) {
  union { float f; unsigned int u; } x{f};
  unsigned int r = x.u + 0x7fffu + ((x.u >> 16) & 1u);   // RNE
  return (ushortT)(r >> 16);
}

// ---------------------------------------------------------------------------
// K0: cast fp32 inputs/weights -> bf16 workspace copies.
// ---------------------------------------------------------------------------
struct US8 { ushortT u[8]; };

__global__ __launch_bounds__(256) void k_cast(
    const float* __restrict__ q, const float* __restrict__ k,
    const float* __restrict__ v, const float* __restrict__ wi,
    const float* __restrict__ wo,
    ushortT* __restrict__ oq, ushortT* __restrict__ ok,
    ushortT* __restrict__ ov, ushortT* __restrict__ owi,
    ushortT* __restrict__ owo)
{
  const int seg = blockIdx.y;
  const float* src; ushortT* dst; int n;
  if      (seg == 0) { src = q;  dst = oq;  n = XN; }
  else if (seg == 1) { src = k;  dst = ok;  n = XN; }
  else if (seg == 2) { src = v;  dst = ov;  n = XN; }
  else if (seg == 3) { src = wi; dst = owi; n = 3 * Ec * Ec; }
  else               { src = wo; dst = owo; n = Ec * Ec; }
  int base = (blockIdx.x * 256 + threadIdx.x) * 8;
  if (base >= n) return;
  float4 a = *reinterpret_cast<const float4*>(src + base);
  float4 b = *reinterpret_cast<const float4*>(src + base + 4);
  US8 o;
  o.u[0] = f2bf(a.x); o.u[1] = f2bf(a.y); o.u[2] = f2bf(a.z); o.u[3] = f2bf(a.w);
  o.u[4] = f2bf(b.x); o.u[5] = f2bf(b.y); o.u[6] = f2bf(b.z); o.u[7] = f2bf(b.w);
  *reinterpret_cast<US8*>(dst + base) = o;
}

// ---------------------------------------------------------------------------
// K0b: zero out1 (atomic accumulation target; harness poisons with 0xAA).
// ---------------------------------------------------------------------------
__global__ __launch_bounds__(256) void k_zero(float* __restrict__ out1)
{
  int i = (blockIdx.x * 256 + threadIdx.x) * 4;
  float4 z = {0.f, 0.f, 0.f, 0.f};
  *reinterpret_cast<float4*>(out1 + i) = z;
}

// ---------------------------------------------------------------------------
// K1: QKV projection, bf16 MFMA. (unchanged)
// ---------------------------------------------------------------------------
__global__ __launch_bounds__(256) void k_qkv_mfma(
    const ushortT* __restrict__ xq, const ushortT* __restrict__ xk,
    const ushortT* __restrict__ xv, const ushortT* __restrict__ wi,
    const float* __restrict__ bias, ushortT* __restrict__ qkv)
{
  __shared__ __align__(16) ushortT As[128][LDW];
  __shared__ __align__(16) ushortT Bs[128][LDW];
  const int tid = threadIdx.x;
  const int lane = tid & 63, wid = tid >> 6;
  const int wm = wid >> 1, wn = wid & 1;
  const int li = lane & 15, gi = lane >> 4;
  const int m0 = blockIdx.x * 128, n0 = blockIdx.y * 128;
  const int third = n0 >> 10;
  const ushortT* x = (third == 0) ? xq : (third == 1) ? xk : xv;

  f32x4 acc[4][4] = {};

  for (int k0 = 0; k0 < 1024; k0 += 64) {
    __syncthreads();
#pragma unroll
    for (int i = 0; i < 4; ++i) {
      int c = tid + i * 256;                 // 0..1023
      int row = c >> 3, col = (c & 7) * 8;
      *reinterpret_cast<uint4*>(&As[row][col]) =
          *reinterpret_cast<const uint4*>(x + (size_t)(m0 + row) * 1024 + k0 + col);
      *reinterpret_cast<uint4*>(&Bs[row][col]) =
          *reinterpret_cast<const uint4*>(wi + (size_t)(n0 + row) * 1024 + k0 + col);
    }
    __syncthreads();
#pragma unroll
    for (int ks = 0; ks < 2; ++ks) {
      bf16x8 a[4], b[4];
#pragma unroll
      for (int t = 0; t < 4; ++t) {
        a[t] = *reinterpret_cast<const bf16x8*>(&As[wm * 64 + t * 16 + li][ks * 32 + gi * 8]);
        b[t] = *reinterpret_cast<const bf16x8*>(&Bs[wn * 64 + t * 16 + li][ks * 32 + gi * 8]);
      }
#pragma unroll
      for (int mi = 0; mi < 4; ++mi)
#pragma unroll
        for (int ni = 0; ni < 4; ++ni)
          acc[mi][ni] = MFMA_BF16(a[mi], b[ni], acc[mi][ni], 0, 0, 0);
    }
  }

  const float scale = (third == 0) ? 0.125f : 1.0f;
#pragma unroll
  for (int ni = 0; ni < 4; ++ni) {
    int n = n0 + wn * 64 + ni * 16 + li;
    float bv = bias[n];
    int h = (n >> 6) & 15, d = n & 63;
#pragma unroll
    for (int mi = 0; mi < 4; ++mi)
#pragma unroll
      for (int r = 0; r < 4; ++r) {
        int m = m0 + wm * 64 + mi * 16 + gi * 4 + r;
        int b_ = m >> 10, s = m & 1023;
        size_t o = ((((size_t)third * Bc + b_) * Hc + h) * Sc + s) * Dc + d;
        qkv[o] = f2bf((acc[mi][ni][r] + bv) * scale);
      }
  }
}

// ---------------------------------------------------------------------------
// K2: flash attention, bf16 MFMA. Writes ctx + fused offrow = m + ln l + ln 16.
// (unchanged)
// ---------------------------------------------------------------------------
__global__ __launch_bounds__(256) void k_flash_mfma(
    const ushortT* __restrict__ qkv, ushortT* __restrict__ ctx,
    float* __restrict__ offrow)
{
  __shared__ __align__(16) ushortT Qs[64][LDW];
  __shared__ __align__(16) ushortT Ks[64][LDW];
  __shared__ __align__(16) ushortT Vt[64][LDW];   // [d][k'] permuted
  __shared__ __align__(16) ushortT Ps[64][LDW];   // [q][k'] permuted
  const int tid = threadIdx.x;
  const int lane = tid & 63, w = tid >> 6;
  const int li = lane & 15, gi = lane >> 4;
  const int s0 = blockIdx.x * 64;
  const int bh = blockIdx.z * Hc + blockIdx.y;
  const ushortT* Q = qkv;
  const ushortT* K = qkv + (size_t)XN;
  const ushortT* V = qkv + (size_t)2 * XN;
  const size_t bhb = (size_t)bh * Sc * Dc;

#pragma unroll
  for (int i = 0; i < 2; ++i) {
    int c = tid + i * 256;
    int row = c >> 3, col = (c & 7) * 8;
    *reinterpret_cast<uint4*>(&Qs[row][col]) =
        *reinterpret_cast<const uint4*>(Q + bhb + (size_t)(s0 + row) * 64 + col);
  }

  f32x4 oa[4] = {};
  float m_r[4], l_r[4];
#pragma unroll
  for (int r = 0; r < 4; ++r) { m_r[r] = -1e30f; l_r[r] = 0.f; }

  // V staging map: pair id vp in [0,32), d-chunk vd0; pair rows (ka, ka+16)
  const int vp = tid & 31;
  const int vd0 = (tid >> 5) * 8;
  const int ka = (vp & 15) + (vp >> 4) * 32;
  const int kpb = 8 * (vp & 15) + 4 * (vp >> 4);  // byte offset of k'-pair in Vt row

  for (int kt = 0; kt < 16; ++kt) {
    const int k0 = kt * 64;
    uint4 kreg[2];
#pragma unroll
    for (int i = 0; i < 2; ++i) {
      int c = tid + i * 256;
      int row = c >> 3, col = (c & 7) * 8;
      kreg[i] = *reinterpret_cast<const uint4*>(K + bhb + (size_t)(k0 + row) * 64 + col);
    }
    uint4 va = *reinterpret_cast<const uint4*>(V + bhb + (size_t)(k0 + ka) * 64 + vd0);
    uint4 vb = *reinterpret_cast<const uint4*>(V + bhb + (size_t)(k0 + ka + 16) * 64 + vd0);
    __syncthreads();   // prior tile's LDS reads complete
#pragma unroll
    for (int i = 0; i < 2; ++i) {
      int c = tid + i * 256;
      int row = c >> 3, col = (c & 7) * 8;
      *reinterpret_cast<uint4*>(&Ks[row][col]) = kreg[i];
    }
    const ushortT* pa_ = reinterpret_cast<const ushortT*>(&va);
    const ushortT* pb_ = reinterpret_cast<const ushortT*>(&vb);
#pragma unroll
    for (int i = 0; i < 8; ++i) {
      unsigned int u = (unsigned int)pa_[i] | ((unsigned int)pb_[i] << 16);
      *reinterpret_cast<unsigned int*>(
          reinterpret_cast<char*>(&Vt[vd0 + i][0]) + kpb) = u;
    }
    __syncthreads();   // staged

    // QK^T
    f32x4 sc[4] = {};
#pragma unroll
    for (int ds = 0; ds < 2; ++ds) {
      bf16x8 aq = *reinterpret_cast<const bf16x8*>(&Qs[w * 16 + li][ds * 32 + gi * 8]);
#pragma unroll
      for (int nf = 0; nf < 4; ++nf) {
        bf16x8 bk = *reinterpret_cast<const bf16x8*>(&Ks[nf * 16 + li][ds * 32 + gi * 8]);
        sc[nf] = MFMA_BF16(aq, bk, sc[nf], 0, 0, 0);
      }
    }

    // online softmax (wave-local; rows r live in acc component r)
    float esc[4];
#pragma unroll
    for (int r = 0; r < 4; ++r) {
      float v = fmaxf(fmaxf(sc[0][r], sc[1][r]), fmaxf(sc[2][r], sc[3][r]));
      v = fmaxf(v, __shfl_xor(v, 1));
      v = fmaxf(v, __shfl_xor(v, 2));
      v = fmaxf(v, __shfl_xor(v, 4));
      v = fmaxf(v, __shfl_xor(v, 8));
      float mnew = fmaxf(m_r[r], v);
      esc[r] = __expf(m_r[r] - mnew);
      m_r[r] = mnew;
    }
    float p[4][4];
#pragma unroll
    for (int r = 0; r < 4; ++r) {
      float s = 0.f;
#pragma unroll
      for (int nf = 0; nf < 4; ++nf) { p[nf][r] = __expf(sc[nf][r] - m_r[r]); s += p[nf][r]; }
      s += __shfl_xor(s, 1); s += __shfl_xor(s, 2);
      s += __shfl_xor(s, 4); s += __shfl_xor(s, 8);
      l_r[r] = l_r[r] * esc[r] + s;
#pragma unroll
      for (int nf = 0; nf < 4; ++nf) oa[nf][r] *= esc[r];
    }
    // pack P (bf16) into Ps rows (wave-private): cols k' = 4*li + nf
#pragma unroll
    for (int r = 0; r < 4; ++r) {
      unsigned int u0 = (unsigned int)f2bf(p[0][r]) | ((unsigned int)f2bf(p[1][r]) << 16);
      unsigned int u1 = (unsigned int)f2bf(p[2][r]) | ((unsigned int)f2bf(p[3][r]) << 16);
      uint2 uu; uu.x = u0; uu.y = u1;
      *reinterpret_cast<uint2*>(
          reinterpret_cast<char*>(&Ps[w * 16 + gi * 4 + r][0]) + li * 8) = uu;
    }
    // PV (contraction over permuted k'; P and Vt use the same permutation)
#pragma unroll
    for (int ks = 0; ks < 2; ++ks) {
      bf16x8 pa = *reinterpret_cast<const bf16x8*>(&Ps[w * 16 + li][ks * 32 + gi * 8]);
#pragma unroll
      for (int nf = 0; nf < 4; ++nf) {
        bf16x8 vv = *reinterpret_cast<const bf16x8*>(&Vt[nf * 16 + li][ks * 32 + gi * 8]);
        oa[nf] = MFMA_BF16(pa, vv, oa[nf], 0, 0, 0);
      }
    }
  }

  float inv[4];
#pragma unroll
  for (int r = 0; r < 4; ++r) inv[r] = 1.0f / l_r[r];
#pragma unroll
  for (int nf = 0; nf < 4; ++nf)
#pragma unroll
    for (int r = 0; r < 4; ++r) {
      int q = s0 + w * 16 + gi * 4 + r;
      ctx[bhb + (size_t)q * 64 + nf * 16 + li] = f2bf(oa[nf][r] * inv[r]);
    }
  if (li == 0) {
#pragma unroll
    for (int r = 0; r < 4; ++r) {
      int q = s0 + w * 16 + gi * 4 + r;
      // fused softmax offset: exp(s - off) = exp(s - m) / (16 * l)
      offrow[(size_t)bh * Sc + q] = m_r[r] + __logf(l_r[r]) + 2.77258872f;
    }
  }
}

// ---------------------------------------------------------------------------
// K3: out projection, bf16 MFMA. (unchanged)
// ---------------------------------------------------------------------------
__global__ __launch_bounds__(256) void k_outproj_mfma(
    const ushortT* __restrict__ ctx, const ushortT* __restrict__ wo,
    const float* __restrict__ bias, float* __restrict__ out)
{
  __shared__ __align__(16) ushortT As[128][LDW];
  __shared__ __align__(16) ushortT Bs[128][LDW];
  const int tid = threadIdx.x;
  const int lane = tid & 63, wid = tid >> 6;
  const int wm = wid >> 1, wn = wid & 1;
  const int li = lane & 15, gi = lane >> 4;
  const int m0 = blockIdx.x * 128, n0 = blockIdx.y * 128;

  f32x4 acc[4][4] = {};

  for (int k0 = 0; k0 < 1024; k0 += 64) {
    const int h = k0 >> 6;          // BK==Dc: one head per K-step
    __syncthreads();
#pragma unroll
    for (int i = 0; i < 4; ++i) {
      int c = tid + i * 256;
      int row = c >> 3, col = (c & 7) * 8;    // col < 64 == within head
      int m = m0 + row;
      int b_ = m >> 10, s = m & 1023;
      *reinterpret_cast<uint4*>(&As[row][col]) =
          *reinterpret_cast<const uint4*>(
              ctx + (((size_t)b_ * Hc + h) * Sc + s) * Dc + col);
      *reinterpret_cast<uint4*>(&Bs[row][col]) =
          *reinterpret_cast<const uint4*>(wo + (size_t)(n0 + row) * 1024 + k0 + col);
    }
    __syncthreads();
#pragma unroll
    for (int ks = 0; ks < 2; ++ks) {
      bf16x8 a[4], b[4];
#pragma unroll
      for (int t = 0; t < 4; ++t) {
        a[t] = *reinterpret_cast<const bf16x8*>(&As[wm * 64 + t * 16 + li][ks * 32 + gi * 8]);
        b[t] = *reinterpret_cast<const bf16x8*>(&Bs[wn * 64 + t * 16 + li][ks * 32 + gi * 8]);
      }
#pragma unroll
      for (int mi = 0; mi < 4; ++mi)
#pragma unroll
        for (int ni = 0; ni < 4; ++ni)
          acc[mi][ni] = MFMA_BF16(a[mi], b[ni], acc[mi][ni], 0, 0, 0);
    }
  }

#pragma unroll
  for (int ni = 0; ni < 4; ++ni) {
    int n = n0 + wn * 64 + ni * 16 + li;
    float bv = bias[n];
#pragma unroll
    for (int mi = 0; mi < 4; ++mi)
#pragma unroll
      for (int r = 0; r < 4; ++r) {
        int m = m0 + wm * 64 + mi * 16 + gi * 4 + r;
        out[(size_t)m * 1024 + n] = acc[mi][ni][r] + bv;
      }
  }
}

// ---------------------------------------------------------------------------
// K4: head-averaged attention weights (partial over 4 heads), bf16 MFMA,
// NO LDS. Head reduction split across 4 blocks (z = b*4+hg) to cut the
// per-wave sequential latency chain 16 -> 4 iterations (the 88us plateau
// was chain-bound: ~13K cyc/iter of serialized L2/L3 misses at VGPR~50).
// Partial sums atomicAdd into zero-initialized out1; gate applied in K5.
// ---------------------------------------------------------------------------
__global__ __launch_bounds__(256) void k_avggate_part(
    const ushortT* __restrict__ qkv, const float* __restrict__ offrow,
    float* __restrict__ out1)
{
  const int tid = threadIdx.x;
  const int lane = tid & 63, w = tid >> 6;
  const int li = lane & 15, gi = lane >> 4;
  const int c0 = blockIdx.x * 64;
  const int s0 = blockIdx.y * 64;
  const int b  = blockIdx.z >> 2;
  const int hg = blockIdx.z & 3;
  constexpr size_t HS = (size_t)Sc * Dc;            // per-head elements
  const ushortT* Qb = qkv + (size_t)b * Hc * HS;
  const ushortT* Kb = qkv + (size_t)XN + (size_t)b * Hc * HS;

  const int qrow = s0 + w * 16 + li;                // A-frag row (per lane)
  const int qoff = s0 + w * 16 + gi * 4;            // C/D rows (per lane)
  f32x4 avg[4] = {};

  for (int hi = 0; hi < 4; ++hi) {
    const int h = hg * 4 + hi;
    const ushortT* Qh = Qb + (size_t)h * HS;
    const ushortT* Kh = Kb + (size_t)h * HS;

    float4 of = *reinterpret_cast<const float4*>(
        offrow + ((size_t)b * Hc + h) * Sc + qoff);
    float ofa[4] = {of.x, of.y, of.z, of.w};

    f32x4 sc[4] = {};
#pragma unroll
    for (int ds = 0; ds < 2; ++ds) {
      bf16x8 aq = *reinterpret_cast<const bf16x8*>(
          Qh + (size_t)qrow * 64 + ds * 32 + gi * 8);
#pragma unroll
      for (int nf = 0; nf < 4; ++nf) {
        bf16x8 bk = *reinterpret_cast<const bf16x8*>(
            Kh + (size_t)(c0 + nf * 16 + li) * 64 + ds * 32 + gi * 8);
        sc[nf] = MFMA_BF16(aq, bk, sc[nf], 0, 0, 0);
      }
    }
#pragma unroll
    for (int nf = 0; nf < 4; ++nf)
#pragma unroll
      for (int r = 0; r < 4; ++r)
        avg[nf][r] += __expf(sc[nf][r] - ofa[r]);
  }

#pragma unroll
  for (int nf = 0; nf < 4; ++nf)
#pragma unroll
    for (int r = 0; r < 4; ++r) {
      int q = qoff + r;
      size_t o = ((size_t)b * Sc + q) * Sc + c0 + nf * 16 + li;
      atomicAdd(&out1[o], avg[nf][r]);
    }
}

// ---------------------------------------------------------------------------
// K5: gate + in-place row renormalization: y = x*g; y /= (sum(y) + 1e-12)
// ---------------------------------------------------------------------------
__global__ __launch_bounds__(256) void k_renorm_gate(
    float* __restrict__ out1, const float* __restrict__ gate)
{
  __shared__ float wsum[4];
  const int tid = threadIdx.x;
  const size_t base = (size_t)blockIdx.x * Sc + tid * 4;
  float4 v = *reinterpret_cast<const float4*>(out1 + base);
  float4 g = *reinterpret_cast<const float4*>(gate + base);
  v.x *= g.x; v.y *= g.y; v.z *= g.z; v.w *= g.w;
  float s = v.x + v.y + v.z + v.w;
#pragma unroll
  for (int off = 1; off < 64; off <<= 1) s += __shfl_xor(s, off);
  if ((tid & 63) == 0) wsum[tid >> 6] = s;
  __syncthreads();
  float inv = 1.0f / (wsum[0] + wsum[1] + wsum[2] + wsum[3] + 1e-12f);
  v.x *= inv; v.y *= inv; v.z *= inv; v.w *= inv;
  *reinterpret_cast<float4*>(out1 + base) = v;
}

// ---------------------------------------------------------------------------
extern "C" void kernel_launch(void* const* d_in, const int* in_sizes, int n_in,
                              void* d_out, int out_size, void* d_ws, size_t ws_size,
                              hipStream_t stream) {
  const float* query = (const float*)d_in[0];
  const float* key   = (const float*)d_in[1];
  const float* value = (const float*)d_in[2];
  const float* gate  = (const float*)d_in[3];
  const float* w_in  = (const float*)d_in[4];
  const float* b_in  = (const float*)d_in[5];
  const float* w_out = (const float*)d_in[6];
  const float* b_out = (const float*)d_in[7];

  float* out0 = (float*)d_out;                       // attn_output (B,S,E)
  float* out1 = out0 + (size_t)Bc * Sc * Ec;         // gated (B,S,S)

  // bf16 workspace layout (ushort elements)
  ushortT* xq   = (ushortT*)d_ws;                    // 4M
  ushortT* xk   = xq + (size_t)XN;                   // 4M
  ushortT* xv   = xk + (size_t)XN;                   // 4M
  ushortT* wi   = xv + (size_t)XN;                   // 3M
  ushortT* wo   = wi + (size_t)3 * Ec * Ec;          // 1M
  ushortT* qkvb = wo + (size_t)Ec * Ec;              // 12M (3,B,H,S,D)
  ushortT* ctxb = xq;                                // alias: xq dead after k_qkv
  float* offrow = (float*)(qkvb + (size_t)3 * XN);   // 64K (m + ln l + ln 16)

  hipLaunchKernelGGL(k_zero, dim3(4096), dim3(256), 0, stream, out1);
  hipLaunchKernelGGL(k_cast, dim3(2048, 5), dim3(256), 0, stream,
                     query, key, value, w_in, w_out, xq, xk, xv, wi, wo);
  hipLaunchKernelGGL(k_qkv_mfma, dim3(32, 24), dim3(256), 0, stream,
                     xq, xk, xv, wi, b_in, qkvb);
  hipLaunchKernelGGL(k_flash_mfma, dim3(16, 16, 4), dim3(256), 0, stream,
                     qkvb, ctxb, offrow);
  hipLaunchKernelGGL(k_outproj_mfma, dim3(32, 8), dim3(256), 0, stream,
                     ctxb, wo, b_out, out0);
  hipLaunchKernelGGL(k_avggate_part, dim3(16, 16, 16), dim3(256), 0, stream,
                     qkvb, offrow, out1);
  hipLaunchKernelGGL(k_renorm_gate, dim3(Bc * Sc), dim3(256), 0, stream,
                     out1, gate);
}